// Round 4
// baseline (666.203 us; speedup 1.0000x reference)
//
#include <hip/hip_runtime.h>

#define BB 256
#define TT 512
#define NN 128
#define GO_IDX 1
#define EOS_IDX 2
#define TSPLIT 180            // bp steps t in [1,TSPLIT) in LDS; [TSPLIT,512) spilled into consumed unary rows
#define NEGV (-10000.0f)
// padded alpha slot: x + (x>>5)*4  -> quarter bases at 0,36,72,108 (banks 0,4,8,12; 16B aligned)
#define ASLOT(x) ((x) + (((x) >> 5) << 2))

// ---------- DPP quad_perm helpers ----------
__device__ __forceinline__ float dpp_xor1_f(float x) {      // quad_perm [1,0,3,2]
    return __int_as_float(__builtin_amdgcn_update_dpp(0, __float_as_int(x), 0xB1, 0xF, 0xF, true));
}
__device__ __forceinline__ float dpp_xor2_f(float x) {      // quad_perm [2,3,0,1]
    return __int_as_float(__builtin_amdgcn_update_dpp(0, __float_as_int(x), 0x4E, 0xF, 0xF, true));
}
__device__ __forceinline__ int dpp_xor1_i(int x) {
    return __builtin_amdgcn_update_dpp(0, x, 0xB1, 0xF, 0xF, true);
}
__device__ __forceinline__ int dpp_xor2_i(int x) {
    return __builtin_amdgcn_update_dpp(0, x, 0x4E, 0xF, 0xF, true);
}

// ---------- fused kernel: 2 INDEPENDENT chains per block (1024 threads) ----------
// Round-3 lesson: s_barrier is workgroup-wide, so sharing it lockstep-couples
// the two chains and serializes their issue. This version gives each chain its
// own software barrier (monotonic LDS counter + ds_add_rtn + spin), so the two
// chains step independently: each SIMD holds 2 waves of each chain, and one
// chain's barrier/LDS-latency stalls are filled by the other's VALU issue.
__global__ __launch_bounds__(1024) void viterbi_kernel(
    float* __restrict__ u,               // [B,T,N] RAW unaries; consumed rows reused as bp spill
    const float* __restrict__ trans,     // [1,N,N] trans0[cur][prev]
    const int*   __restrict__ lengths_raw,
    float* __restrict__ out)             // [B*T] preds then [B] scores
{
    __shared__ unsigned char bps[2][(TSPLIT - 1) * NN];   // 2 x 22912 B
    __shared__ __align__(16) float prob[2][2][8][NN];     // 2 x 8192 B, normalized rows (dbuf); reused as bp cache
    __shared__ __align__(16) float alpha[2][2][144];      // 2 x 1152 B; reused as last_tag/H tables in epilogue
    __shared__ float fin_v[2][2];
    __shared__ int   fin_i[2][2];
    __shared__ unsigned int barctr[2];                    // per-chain monotonic barrier counter

    const int tid  = threadIdx.x;
    const int bi   = tid >> 9;             // chain within block (0/1)
    const int lt   = tid & 511;            // local tid within chain
    const int b    = (blockIdx.x << 1) | bi;
    const int wv   = lt >> 6;              // wave within chain 0..7
    const int lane = lt & 63;
    const int q    = lt & 3;               // prev-quarter owned by this lane
    const int cur  = lt >> 2;              // tag owned by this quad (0..127)
    const int hwr  = lt >> 5;              // half-wave within chain 0..15 (lsm row owner when <8)
    const int l32  = lt & 31;

    int len;
    {
        int probe = lengths_raw[1];        // ==0 iff int64 (lengths >= 256 > 0)
        len = (probe == 0) ? lengths_raw[2 * b] : lengths_raw[b];
    }

    float* pb = u + (size_t)b * TT * NN;
    const float4* pb4 = (const float4*)pb;

    // trans chunk in registers: trans0[cur][q*32 + j], j in [0,32)
    float tr[32];
    {
        const float4* t4 = (const float4*)(trans + cur * NN + q * 32);
#pragma unroll
        for (int i = 0; i < 8; ++i) {
            float4 v = t4[i];
            tr[4*i+0] = v.x; tr[4*i+1] = v.y; tr[4*i+2] = v.z; tr[4*i+3] = v.w;
        }
    }

    if (tid < 2) barctr[tid] = 0u;
    if (lt < NN) alpha[bi][0][ASLOT(lt)] = (lt == GO_IDX) ? 0.0f : NEGV;

    // per-chain software step barrier: drain own LDS ops, arrive, spin until
    // all 8 waves of THIS chain arrived. Global prefetch loads stay in flight
    // (only lgkmcnt is drained). Lane 0 spins; wave lockstep holds the rest.
    auto chain_sync = [&]() {
        asm volatile("s_waitcnt lgkmcnt(0)" ::: "memory");
        if (lane == 0) {
            unsigned int old = atomicAdd(&barctr[bi], 1u);
            unsigned int tgt = ((old >> 3) + 1u) << 3;
            while (*((volatile unsigned int*)&barctr[bi]) < tgt)
                __builtin_amdgcn_s_sleep(1);
        }
        asm volatile("" ::: "memory");
    };

    // per-row log_softmax, bitwise-identical to the proven math
    auto normrow = [&](float4 v, float* dstrow) {
        float m = fmaxf(fmaxf(v.x, v.y), fmaxf(v.z, v.w));
#pragma unroll
        for (int off = 16; off; off >>= 1) m = fmaxf(m, __shfl_xor(m, off, 64));
        float s = expf(v.x - m) + expf(v.y - m) + expf(v.z - m) + expf(v.w - m);
#pragma unroll
        for (int off = 16; off; off >>= 1) s += __shfl_xor(s, off, 64);
        float ls = logf(s);
        ((float4*)dstrow)[l32] =
            make_float4((v.x - m) - ls, (v.y - m) - ls, (v.z - m) - ls, (v.w - m) - ls);
    };

    // prologue (norm waves = waves 0..3 of each chain, wave-uniform guard):
    // rows 0..7 -> buf0; rows 8..15 -> R (normalized at top of g=0)
    float4 R;
    if (lt < 256) {
        R = pb4[hwr * 32 + l32];
        normrow(R, &prob[bi][0][hwr][0]);
        R = pb4[(8 + hwr) * 32 + l32];
    }
    __syncthreads();   // covers barctr/alpha init + buf0 for both chains

    const int nG = (len + 7) >> 3;         // chain-local bound: chains iterate independently
    for (int g = 0; g < nG; ++g) {
        const int tb = g << 3;
        if (lt < 256) {
            // normalize rows of group g+1 (loaded last group) -> buf[(g+1)&1]
            normrow(R, &prob[bi][(g + 1) & 1][hwr][0]);
            // issue raw loads for group g+2 (stay in flight across step syncs)
            int rr = tb + 16 + hwr;
            if (rr > TT - 1) rr = TT - 1;   // clamped row never normalized/used
            R = pb4[rr * 32 + l32];
        }
#pragma unroll 4
        for (int k = 0; k < 8; ++k) {
            const int t = tb + k;
            if (t < len) {                         // uniform per chain
                const float Pv = prob[bi][g & 1][k][cur];   // broadcast ds_read_b32
                const float* ra = alpha[bi][t & 1];
                float*       wa = alpha[bi][(t & 1) ^ 1];
                const float4* a4 = (const float4*)(ra + q * 36);  // banks 0/4/8/12 per quarter
                float bv[4]; int bi4[4];
#pragma unroll
                for (int c = 0; c < 4; ++c) {      // 4 chains x 8 prevs, ascending strict >
                    float4 a0 = a4[c * 2], a1 = a4[c * 2 + 1];
                    const int base = c * 8;
                    bv[c] = a0.x + tr[base + 0]; bi4[c] = base + 0;
                    float x;
                    x = a0.y + tr[base + 1]; if (x > bv[c]) { bv[c] = x; bi4[c] = base + 1; }
                    x = a0.z + tr[base + 2]; if (x > bv[c]) { bv[c] = x; bi4[c] = base + 2; }
                    x = a0.w + tr[base + 3]; if (x > bv[c]) { bv[c] = x; bi4[c] = base + 3; }
                    x = a1.x + tr[base + 4]; if (x > bv[c]) { bv[c] = x; bi4[c] = base + 4; }
                    x = a1.y + tr[base + 5]; if (x > bv[c]) { bv[c] = x; bi4[c] = base + 5; }
                    x = a1.z + tr[base + 6]; if (x > bv[c]) { bv[c] = x; bi4[c] = base + 6; }
                    x = a1.w + tr[base + 7]; if (x > bv[c]) { bv[c] = x; bi4[c] = base + 7; }
                }
                float best = bv[0]; int bp = bi4[0];
#pragma unroll
                for (int c = 1; c < 4; ++c) { if (bv[c] > best) { best = bv[c]; bp = bi4[c]; } }
                bp += q * 32;                      // absolute prev index

                // DPP quad combine (value + index). Tie-break identical to proven version.
                float v1 = dpp_xor1_f(best); int b1 = dpp_xor1_i(bp);
                bool  t1 = (q & 1) ? (v1 >= best) : (v1 > best);
                float m1 = t1 ? v1 : best;   int p1 = t1 ? b1 : bp;
                float v2 = dpp_xor2_f(m1);   int b2 = dpp_xor2_i(p1);
                bool  t2 = (q & 2) ? (v2 >= m1) : (v2 > m1);
                float M  = t2 ? v2 : m1;     int BP = t2 ? b2 : p1;

                if (q == 0) {
                    wa[ASLOT(cur)] = M + Pv;
                    if (t >= 1) {
                        if (t < TSPLIT) bps[bi][(t - 1) * NN + cur] = (unsigned char)BP;
                        else ((unsigned char*)pb)[(size_t)t * 512 + cur] = (unsigned char)BP;
                        // spill into row t's first 128 bytes: row t fully consumed
                        // (prefetch only touches rows >= t+16)
                    }
                }
            }
            chain_sync();      // per-chain only: other chain unaffected
        }
    }

    __threadfence();   // spilled bp global writes visible to this block's readers

    // terminal: argmax(alpha + trans0[EOS][:]), first-max tie-break
    if (lt < NN) {
        float v = alpha[bi][len & 1][ASLOT(lt)] + trans[EOS_IDX * NN + lt];
        int idx = lt;
#pragma unroll
        for (int off = 32; off; off >>= 1) {
            float ov = __shfl_xor(v, off, 64);
            int   oi = __shfl_xor(idx, off, 64);
            if (ov > v || (ov == v && oi < idx)) { v = ov; idx = oi; }
        }
        if (lane == 0) { fin_v[bi][wv] = v; fin_i[bi][wv] = idx; }
    }
    __syncthreads();   // hardware barrier: both chains done; full drain

    const int lenU = __builtin_amdgcn_readfirstlane(len);

    for (int t = lenU + lt; t < TT; t += 512) out[(size_t)b * TT + t] = 0.0f;

    // stage spilled bp steps [TSPLIT, TSPLIT+64) into the (now free) prob LDS.
    {
        unsigned int* cache = (unsigned int*)&prob[bi][0][0][0];      // 8192 B per chain
        const volatile unsigned int* src = (const volatile unsigned int*)pb;
        for (int i = lt; i < 64 * 32; i += 512)
            cache[i] = src[(size_t)(TSPLIT + (i >> 5)) * 128 + (i & 31)];
    }
    __syncthreads();

    // terminal winner (uniform across the chain's threads)
    float sc; int T0;
    {
        float v0 = fin_v[bi][0], v1 = fin_v[bi][1];
        int   i0 = fin_i[bi][0], i1 = fin_i[bi][1];
        if (v1 > v0) { sc = v1; T0 = i1; }
        else         { sc = v0; T0 = i0; }
    }
    if (lt == 0) {
        out[(size_t)BB * TT + b] = sc;
        out[(size_t)b * TT + (lenU - 1)] = (float)T0;
    }

    // ---------- parallel hypothesis backtrace ----------
    // 8 segments of 64 links per chain; wave s chases segment s for all 128
    // entry tags (2 hypotheses/lane), replaying the exact serial byte loads.
    const unsigned char* cacheb = (const unsigned char*)&prob[bi][0][0][0];
    unsigned char* lt_tab = (unsigned char*)&alpha[bi][0][0];  // last_tag[8][128] overlay (alpha dead)
    unsigned char* Harr   = lt_tab + 1024;                     // H[8] overlay

    const int s  = wv;                     // segment id 0..7
    const int A  = lenU - 1 - 64 * s;      // anchor time of this segment
    const int h0 = lane;                   // hypothesis tags
    const int h1 = 64 + lane;
    const int Jmax = (A < 64) ? A : 64;    // links to follow (A<1 -> none)

    unsigned int rec0[16], rec1[16];
#pragma unroll
    for (int i = 0; i < 16; ++i) { rec0[i] = 0u; rec1[i] = 0u; }

    int c0 = h0, c1 = h1;
#pragma unroll
    for (int j = 1; j <= 64; ++j) {
        if (j <= Jmax) {                   // wave-uniform
            const int x = A - j + 1;       // step whose bp we read -> tag at time A-j
            int n0, n1;
            if (x < TSPLIT) {
                n0 = bps[bi][(x - 1) * NN + c0];
                n1 = bps[bi][(x - 1) * NN + c1];
            } else if (x < TSPLIT + 64) {
                n0 = cacheb[(x - TSPLIT) * NN + c0];
                n1 = cacheb[(x - TSPLIT) * NN + c1];
            } else {
                n0 = ((const volatile unsigned char*)pb)[(size_t)x * 512 + c0];
                n1 = ((const volatile unsigned char*)pb)[(size_t)x * 512 + c1];
            }
            c0 = n0; c1 = n1;
            rec0[(j - 1) >> 2] |= (unsigned int)c0 << (((j - 1) & 3) * 8);
            rec1[(j - 1) >> 2] |= (unsigned int)c1 << (((j - 1) & 3) * 8);
        }
    }
    if (A >= 65) {                         // tag at A-64 feeds segment s+1's stitch
        lt_tab[s * NN + h0] = (unsigned char)c0;
        lt_tab[s * NN + h1] = (unsigned char)c1;
    }
    __syncthreads();

    if (lt == 0) {
        int H = T0;
        Harr[0] = (unsigned char)H;
#pragma unroll
        for (int ss = 1; ss < 8; ++ss) {
            if (lenU - 1 - 64 * ss >= 1) {
                H = lt_tab[(ss - 1) * NN + H];
                Harr[ss] = (unsigned char)H;
            }
        }
    }
    __syncthreads();

    if (A >= 1) {
        const int Hs = Harr[s];
        if (h0 == Hs) {
#pragma unroll
            for (int j = 1; j <= 64; ++j)
                if (j <= Jmax)
                    out[(size_t)b * TT + (A - j)] =
                        (float)((rec0[(j - 1) >> 2] >> (((j - 1) & 3) * 8)) & 255u);
        }
        if (h1 == Hs) {
#pragma unroll
            for (int j = 1; j <= 64; ++j)
                if (j <= Jmax)
                    out[(size_t)b * TT + (A - j)] =
                        (float)((rec1[(j - 1) >> 2] >> (((j - 1) & 3) * 8)) & 255u);
        }
    }
}

extern "C" void kernel_launch(void* const* d_in, const int* in_sizes, int n_in,
                              void* d_out, int out_size, void* d_ws, size_t ws_size,
                              hipStream_t stream) {
    float*       unaries = (float*)d_in[0];
    const float* trans   = (const float*)d_in[1];
    const int*   lengths = (const int*)d_in[2];
    float* out = (float*)d_out;
    (void)d_ws; (void)ws_size; (void)in_sizes; (void)n_in; (void)out_size;

    hipLaunchKernelGGL(viterbi_kernel, dim3(BB / 2), dim3(1024), 0, stream,
                       unaries, trans, lengths, out);
}

// Round 5
// 498.978 us; speedup vs baseline: 1.3351x; 1.3351x over previous
//
#include <hip/hip_runtime.h>

#define BB 256
#define TT 512
#define NN 128
#define GO_IDX 1
#define EOS_IDX 2
#define TSPLIT 368            // bp steps t in [1,TSPLIT) in LDS; [TSPLIT,512) spilled (ws or consumed unary rows)
#define NEGV (-10000.0f)
// padded alpha slot: x + (x>>5)*4  -> quarter bases at 0,36,72,108 (banks 0,4,8,12; 16B aligned)
#define ASLOT(x) ((x) + (((x) >> 5) << 2))

// step barrier: drain LDS only (alpha/bps/prob), leave global prefetch loads in flight.
#define STEP_BARRIER() asm volatile("s_waitcnt lgkmcnt(0)\n\ts_barrier" ::: "memory")

typedef float f32x2 __attribute__((ext_vector_type(2)));

// packed f32 add (VOP3P) — same adds as scalar, half the instructions, bit-exact
__device__ __forceinline__ f32x2 pk_add(f32x2 a, f32x2 b) {
    f32x2 d;
    asm("v_pk_add_f32 %0, %1, %2" : "=v"(d) : "v"(a), "v"(b));
    return d;
}

// ---------- DPP quad_perm helpers ----------
__device__ __forceinline__ float dpp_xor1_f(float x) {      // quad_perm [1,0,3,2]
    return __int_as_float(__builtin_amdgcn_update_dpp(0, __float_as_int(x), 0xB1, 0xF, 0xF, true));
}
__device__ __forceinline__ float dpp_xor2_f(float x) {      // quad_perm [2,3,0,1]
    return __int_as_float(__builtin_amdgcn_update_dpp(0, __float_as_int(x), 0x4E, 0xF, 0xF, true));
}
__device__ __forceinline__ int dpp_xor1_i(int x) {
    return __builtin_amdgcn_update_dpp(0, x, 0xB1, 0xF, 0xF, true);
}
__device__ __forceinline__ int dpp_xor2_i(int x) {
    return __builtin_amdgcn_update_dpp(0, x, 0x4E, 0xF, 0xF, true);
}

// ---------- fused kernel: in-flight log_softmax + serial Viterbi ----------
// Round-2 proven structure (single chain per block, 512 threads, hw s_barrier).
// This round: issue-side trim only — launch_bounds(512,2) to lift the VGPR cap
// (only 1 block/CU ever resident, registers are free), v_pk_add_f32 for the
// alpha+tr adds, and value-combine/write before index-combine so the alpha
// ds_write latency overlaps the backpointer tail.
// USE_WS=1: bp spill to d_ws; USE_WS=0: spill into consumed unary rows.
template <int USE_WS>
__global__ __launch_bounds__(512, 2) void viterbi_kernel(
    float* __restrict__ u,               // [B,T,N] RAW unaries
    const float* __restrict__ trans,     // [1,N,N] trans0[cur][prev]
    const int*   __restrict__ lengths_raw,
    float* __restrict__ out,             // [B*T] preds then [B] scores
    unsigned char* __restrict__ ws)      // spill: [B][144][128] bytes when USE_WS
{
    __shared__ unsigned char bps[(TSPLIT - 1) * NN];   // 46976 B (steps 1..367 at row t-1)
    __shared__ __align__(16) float prob[2][16][NN];    // 16384 B, normalized rows (dbuf); reused as bp cache
    __shared__ __align__(16) float alpha[2][144];      // 1152 B; reused as last_tag/H tables in epilogue
    __shared__ float fin_v[2];
    __shared__ int   fin_i[2];

    const int tid  = threadIdx.x;
    const int b    = blockIdx.x;
    const int wave = tid >> 6;
    const int lane = tid & 63;
    const int q    = tid & 3;              // prev-quarter owned by this lane
    const int cur  = tid >> 2;             // tag owned by this quad (0..127)
    const int hw   = tid >> 5;             // half-wave id 0..15 (lsm row owner)
    const int l32  = tid & 31;

    int len;
    {
        int probe = lengths_raw[1];        // ==0 iff int64 (lengths >= 256 > 0)
        len = (probe == 0) ? lengths_raw[2 * b] : lengths_raw[b];
    }

    float* pb = u + (size_t)b * TT * NN;
    const float4* pb4 = (const float4*)pb;
    unsigned char* spb = USE_WS ? (ws + (size_t)b * ((TT - TSPLIT) * NN)) : (unsigned char*)pb;

    // trans chunk in register PAIRS: tr2[c*4+j] = trans0[cur][q*32 + c*8 + 2j .. +1]
    f32x2 tr2[16];
    {
        const float4* t4 = (const float4*)(trans + cur * NN + q * 32);
#pragma unroll
        for (int i = 0; i < 8; ++i) {
            float4 v = t4[i];
            f32x2 lo; lo.x = v.x; lo.y = v.y;
            f32x2 hi; hi.x = v.z; hi.y = v.w;
            tr2[2 * i]     = lo;
            tr2[2 * i + 1] = hi;
        }
    }

    if (tid < NN) alpha[0][ASLOT(tid)] = (tid == GO_IDX) ? 0.0f : NEGV;

    // per-row log_softmax, bitwise-identical to the proven math
    auto normrow = [&](float4 v, float* dstrow) {
        float m = fmaxf(fmaxf(v.x, v.y), fmaxf(v.z, v.w));
#pragma unroll
        for (int off = 16; off; off >>= 1) m = fmaxf(m, __shfl_xor(m, off, 64));
        float s = expf(v.x - m) + expf(v.y - m) + expf(v.z - m) + expf(v.w - m);
#pragma unroll
        for (int off = 16; off; off >>= 1) s += __shfl_xor(s, off, 64);
        float ls = logf(s);
        ((float4*)dstrow)[l32] =
            make_float4((v.x - m) - ls, (v.y - m) - ls, (v.z - m) - ls, (v.w - m) - ls);
    };

    // prologue: rows 0..15 -> buf0; rows 16..31 -> R (normalized at top of g=0)
    float4 R = pb4[hw * 32 + l32];
    normrow(R, &prob[0][hw][0]);
    R = pb4[(16 + hw) * 32 + l32];
    __syncthreads();

    const int nG = (len + 15) >> 4;
    for (int g = 0; g < nG; ++g) {
        const int tb = g << 4;
        // normalize rows of group g+1 (loaded last group) -> buf[(g+1)&1].
        normrow(R, &prob[(g + 1) & 1][hw][0]);
        // issue raw loads for group g+2 (stay in flight across step barriers)
        {
            int rr = tb + 32 + hw;
            if (rr > TT - 1) rr = TT - 1;   // clamped row never normalized/used
            R = pb4[rr * 32 + l32];
        }
#pragma unroll 4
        for (int k = 0; k < 16; ++k) {
            const int t = tb + k;
            if (t < len) {                         // uniform per block
                const float Pv = prob[g & 1][k][cur];   // broadcast ds_read_b32
                const float* ra = alpha[t & 1];
                float*       wa = alpha[(t & 1) ^ 1];
                const float4* a4 = (const float4*)(ra + q * 36);  // banks 0/4/8/12 per quarter
                float bv[4]; int bi4[4];
#pragma unroll
                for (int c = 0; c < 4; ++c) {      // 4 chains x 8 prevs, ascending strict >
                    float4 a0 = a4[c * 2], a1 = a4[c * 2 + 1];
                    f32x2 p0; p0.x = a0.x; p0.y = a0.y;
                    f32x2 p1; p1.x = a0.z; p1.y = a0.w;
                    f32x2 p2; p2.x = a1.x; p2.y = a1.y;
                    f32x2 p3; p3.x = a1.z; p3.y = a1.w;
                    f32x2 s0 = pk_add(p0, tr2[c * 4 + 0]);
                    f32x2 s1 = pk_add(p1, tr2[c * 4 + 1]);
                    f32x2 s2 = pk_add(p2, tr2[c * 4 + 2]);
                    f32x2 s3 = pk_add(p3, tr2[c * 4 + 3]);
                    const int base = c * 8;
                    bv[c] = s0.x; bi4[c] = base + 0;
                    float x;
                    x = s0.y; if (x > bv[c]) { bv[c] = x; bi4[c] = base + 1; }
                    x = s1.x; if (x > bv[c]) { bv[c] = x; bi4[c] = base + 2; }
                    x = s1.y; if (x > bv[c]) { bv[c] = x; bi4[c] = base + 3; }
                    x = s2.x; if (x > bv[c]) { bv[c] = x; bi4[c] = base + 4; }
                    x = s2.y; if (x > bv[c]) { bv[c] = x; bi4[c] = base + 5; }
                    x = s3.x; if (x > bv[c]) { bv[c] = x; bi4[c] = base + 6; }
                    x = s3.y; if (x > bv[c]) { bv[c] = x; bi4[c] = base + 7; }
                }
                float best = bv[0]; int bp = bi4[0];
#pragma unroll
                for (int c = 1; c < 4; ++c) { if (bv[c] > best) { best = bv[c]; bp = bi4[c]; } }
                bp += q * 32;                      // absolute prev index

                // DPP quad combine, VALUE path first (write early), then INDEX
                // path reusing the same t1/t2 predicates — identical result.
                float v1 = dpp_xor1_f(best);
                bool  t1 = (q & 1) ? (v1 >= best) : (v1 > best);
                float m1 = t1 ? v1 : best;
                float v2 = dpp_xor2_f(m1);
                bool  t2 = (q & 2) ? (v2 >= m1) : (v2 > m1);
                float M  = t2 ? v2 : m1;

                if (q == 0) wa[ASLOT(cur)] = M + Pv;   // alpha write issued early

                int b1 = dpp_xor1_i(bp);
                int p1i = t1 ? b1 : bp;
                int b2 = dpp_xor2_i(p1i);
                int BP = t2 ? b2 : p1i;

                if (q == 0 && t >= 1) {
                    if (t < TSPLIT) bps[(t - 1) * NN + cur] = (unsigned char)BP;
                    else if (USE_WS) spb[(t - TSPLIT) * NN + cur] = (unsigned char)BP;
                    else             spb[(size_t)t * 512 + cur] = (unsigned char)BP;
                }
                STEP_BARRIER();    // lgkmcnt(0) only — global prefetch stays in flight
            }
        }
    }

    __threadfence();   // spilled bp global writes visible to this block's readers

    // terminal: argmax(alpha + trans0[EOS][:]), first-max tie-break
    if (tid < NN) {
        float v = alpha[len & 1][ASLOT(tid)] + trans[EOS_IDX * NN + tid];
        int idx = tid;
#pragma unroll
        for (int off = 32; off; off >>= 1) {
            float ov = __shfl_xor(v, off, 64);
            int   oi = __shfl_xor(idx, off, 64);
            if (ov > v || (ov == v && oi < idx)) { v = ov; idx = oi; }
        }
        if (lane == 0) { fin_v[wave] = v; fin_i[wave] = idx; }
    }
    __syncthreads();   // fin ready; full drain (incl. vmcnt) of forward traffic

    const int lenU = __builtin_amdgcn_readfirstlane(len);

    for (int t = lenU + tid; t < TT; t += 512) out[(size_t)b * TT + t] = 0.0f;

    // stage spilled bp steps [TSPLIT, TSPLIT+128) into the (now free) prob LDS.
    {
        unsigned int* cache = (unsigned int*)&prob[0][0][0];          // 16384 B, exact fit
        const volatile unsigned int* src = (const volatile unsigned int*)spb;
        for (int i = tid; i < 128 * 32; i += 512) {
            if (USE_WS) cache[i] = src[(size_t)(i >> 5) * 32 + (i & 31)];
            else        cache[i] = src[(size_t)(TSPLIT + (i >> 5)) * 128 + (i & 31)];
        }
    }
    __syncthreads();

    // terminal winner (uniform across threads)
    float sc; int T0;
    {
        float v0 = fin_v[0], v1 = fin_v[1];
        int   i0 = fin_i[0], i1 = fin_i[1];
        if (v1 > v0) { sc = v1; T0 = i1; }
        else         { sc = v0; T0 = i0; }
    }
    if (tid == 0) {
        out[(size_t)BB * TT + b] = sc;
        out[(size_t)b * TT + (lenU - 1)] = (float)T0;
    }

    // ---------- parallel hypothesis backtrace ----------
    // 8 segments of 64 links; wave s chases segment s for all 128 entry tags
    // (2 hypotheses/lane), replaying the exact same byte loads as a serial chase.
    const unsigned char* cacheb = (const unsigned char*)&prob[0][0][0];
    unsigned char* lt   = (unsigned char*)&alpha[0][0];   // last_tag[8][128] overlay (alpha dead)
    unsigned char* Harr = lt + 1024;                      // H[8] overlay

    const int s  = wave;                   // segment id 0..7
    const int A  = lenU - 1 - 64 * s;      // anchor time of this segment
    const int h0 = lane;                   // hypothesis tags
    const int h1 = 64 + lane;
    const int Jmax = (A < 64) ? A : 64;    // links to follow (A<1 -> none)

    unsigned int rec0[16], rec1[16];
#pragma unroll
    for (int i = 0; i < 16; ++i) { rec0[i] = 0u; rec1[i] = 0u; }

    int c0 = h0, c1 = h1;
#pragma unroll
    for (int j = 1; j <= 64; ++j) {
        if (j <= Jmax) {                   // wave-uniform
            const int x = A - j + 1;       // step whose bp we read -> tag at time A-j
            int n0, n1;
            if (x < TSPLIT) {
                n0 = bps[(x - 1) * NN + c0];
                n1 = bps[(x - 1) * NN + c1];
            } else if (x < TSPLIT + 128) {
                n0 = cacheb[(x - TSPLIT) * NN + c0];
                n1 = cacheb[(x - TSPLIT) * NN + c1];
            } else {
                if (USE_WS) {
                    n0 = ((const volatile unsigned char*)spb)[(size_t)(x - TSPLIT) * NN + c0];
                    n1 = ((const volatile unsigned char*)spb)[(size_t)(x - TSPLIT) * NN + c1];
                } else {
                    n0 = ((const volatile unsigned char*)spb)[(size_t)x * 512 + c0];
                    n1 = ((const volatile unsigned char*)spb)[(size_t)x * 512 + c1];
                }
            }
            c0 = n0; c1 = n1;
            rec0[(j - 1) >> 2] |= (unsigned int)c0 << (((j - 1) & 3) * 8);
            rec1[(j - 1) >> 2] |= (unsigned int)c1 << (((j - 1) & 3) * 8);
        }
    }
    if (A >= 65) {                         // tag at A-64 feeds segment s+1's stitch
        lt[s * NN + h0] = (unsigned char)c0;
        lt[s * NN + h1] = (unsigned char)c1;
    }
    __syncthreads();

    if (tid == 0) {
        int H = T0;
        Harr[0] = (unsigned char)H;
#pragma unroll
        for (int ss = 1; ss < 8; ++ss) {
            if (lenU - 1 - 64 * ss >= 1) {
                H = lt[(ss - 1) * NN + H];
                Harr[ss] = (unsigned char)H;
            }
        }
    }
    __syncthreads();

    if (A >= 1) {
        const int Hs = Harr[s];
        if (h0 == Hs) {
#pragma unroll
            for (int j = 1; j <= 64; ++j)
                if (j <= Jmax)
                    out[(size_t)b * TT + (A - j)] =
                        (float)((rec0[(j - 1) >> 2] >> (((j - 1) & 3) * 8)) & 255u);
        }
        if (h1 == Hs) {
#pragma unroll
            for (int j = 1; j <= 64; ++j)
                if (j <= Jmax)
                    out[(size_t)b * TT + (A - j)] =
                        (float)((rec1[(j - 1) >> 2] >> (((j - 1) & 3) * 8)) & 255u);
        }
    }
}

extern "C" void kernel_launch(void* const* d_in, const int* in_sizes, int n_in,
                              void* d_out, int out_size, void* d_ws, size_t ws_size,
                              hipStream_t stream) {
    float*       unaries = (float*)d_in[0];
    const float* trans   = (const float*)d_in[1];
    const int*   lengths = (const int*)d_in[2];
    float* out = (float*)d_out;
    unsigned char* ws = (unsigned char*)d_ws;

    const size_t need = (size_t)BB * (TT - TSPLIT) * NN;   // 4,718,592 B
    if (ws != nullptr && ws_size >= need) {
        hipLaunchKernelGGL(HIP_KERNEL_NAME(viterbi_kernel<1>), dim3(BB), dim3(512), 0, stream,
                           unaries, trans, lengths, out, ws);
    } else {
        hipLaunchKernelGGL(HIP_KERNEL_NAME(viterbi_kernel<0>), dim3(BB), dim3(512), 0, stream,
                           unaries, trans, lengths, out, ws);
    }
}